// Round 7
// baseline (300.725 us; speedup 1.0000x reference)
//
#include <hip/hip_runtime.h>
#include <hip/hip_bf16.h>

#define BB 8
#define CC 256
#define HH 64
#define WW 64
#define MM 512
#define HWHW 4096

typedef __attribute__((ext_vector_type(4))) float f32x4;
typedef __attribute__((ext_vector_type(8))) short s16x8;

static __device__ __forceinline__ ushort f2bf(float f) {
    unsigned u = __float_as_uint(f);
    unsigned r = ((u >> 16) & 1u) + 0x7fffu;      // RNE
    return (ushort)((u + r) >> 16);
}
static __device__ __forceinline__ float bf2f(ushort u) {
    return __uint_as_float(((unsigned)u) << 16);
}

// ---------------- K_pre: fused {ig | prep | mf} ----------------
__global__ void k_pre(const float* __restrict__ img, const float* __restrict__ mem,
                      const float* __restrict__ fw, float* __restrict__ IG,
                      ushort* __restrict__ membf, float* __restrict__ mf) {
    int bid = blockIdx.x;
    int t = threadIdx.x;
    if (bid < 2048) {
        const float4* p = (const float4*)(img + (size_t)bid * HWHW);
        float s = 0.f;
#pragma unroll
        for (int k = 0; k < 4; k++) {
            float4 v = p[t + 256 * k];
            s += v.x + v.y + v.z + v.w;
        }
#pragma unroll
        for (int off = 32; off > 0; off >>= 1) s += __shfl_down(s, off);
        __shared__ float red[4];
        int wave = t >> 6, lane = t & 63;
        if (lane == 0) red[wave] = s;
        __syncthreads();
        if (t == 0) IG[bid] = (red[0] + red[1] + red[2] + red[3]) * (1.f / 4096.f);
    } else if (bid < 2176) {
        int i = ((bid - 2048) * 256 + t) * 4;
        float4 v = *(const float4*)(mem + i);
        ushort4 o;
        o.x = f2bf(v.x); o.y = f2bf(v.y); o.z = f2bf(v.z); o.w = f2bf(v.w);
        *(ushort4*)(membf + i) = o;
    } else {
        int m0 = (bid - 2176) * 8;
        __shared__ float mrow[8][CC];
#pragma unroll
        for (int j = 0; j < 8; j++) mrow[j][t] = mem[(size_t)(m0 + j) * CC + t];
        __syncthreads();
        const float4* fwr = (const float4*)(fw + (size_t)t * (2 * CC) + CC);
        float acc[8];
#pragma unroll
        for (int j = 0; j < 8; j++) acc[j] = 0.f;
#pragma unroll 8
        for (int ci = 0; ci < 64; ci++) {
            float4 fv = fwr[ci];
#pragma unroll
            for (int j = 0; j < 8; j++) {
                acc[j] = fmaf(mrow[j][ci * 4 + 0], fv.x, acc[j]);
                acc[j] = fmaf(mrow[j][ci * 4 + 1], fv.y, acc[j]);
                acc[j] = fmaf(mrow[j][ci * 4 + 2], fv.z, acc[j]);
                acc[j] = fmaf(mrow[j][ci * 4 + 3], fv.w, acc[j]);
            }
        }
#pragma unroll
        for (int j = 0; j < 8; j++) mf[(size_t)(m0 + j) * CC + t] = acc[j];
    }
}

// ---------------- K2: gate g = sigmoid(softmax(IG@M^T)@M + IG) ----------------
__global__ void k_global(const float* __restrict__ IG, const float* __restrict__ mem,
                         float* __restrict__ g) {
    int b = blockIdx.x;
    int t = threadIdx.x;
    __shared__ float ig[CC];
    __shared__ float sc[MM];
    __shared__ float red[256];
    ig[t] = IG[b * CC + t];
    __syncthreads();
#pragma unroll
    for (int half = 0; half < 2; half++) {
        int m = t + half * 256;
        const float4* mr = (const float4*)(mem + (size_t)m * CC);
        const float4* igr = (const float4*)ig;
        float s0 = 0.f, s1 = 0.f, s2 = 0.f, s3 = 0.f;
#pragma unroll 8
        for (int ci = 0; ci < 64; ci++) {
            float4 mv = mr[ci];
            float4 iv = igr[ci];
            s0 = fmaf(mv.x, iv.x, s0); s1 = fmaf(mv.y, iv.y, s1);
            s2 = fmaf(mv.z, iv.z, s2); s3 = fmaf(mv.w, iv.w, s3);
        }
        sc[m] = (s0 + s1) + (s2 + s3);
    }
    __syncthreads();
    red[t] = fmaxf(sc[t], sc[t + 256]);
    __syncthreads();
    for (int o = 128; o > 0; o >>= 1) {
        if (t < o) red[t] = fmaxf(red[t], red[t + o]);
        __syncthreads();
    }
    float mx = red[0];
    __syncthreads();
    float e0 = expf(sc[t] - mx), e1 = expf(sc[t + 256] - mx);
    red[t] = e0 + e1;
    __syncthreads();
    for (int o = 128; o > 0; o >>= 1) {
        if (t < o) red[t] += red[t + o];
        __syncthreads();
    }
    float inv = 1.f / red[0];
    sc[t] = e0 * inv; sc[t + 256] = e1 * inv;
    __syncthreads();
    float r0 = ig[t], r1 = 0.f, r2 = 0.f, r3 = 0.f;
#pragma unroll 8
    for (int m = 0; m < MM; m += 4) {
        r0 = fmaf(sc[m + 0], mem[(size_t)(m + 0) * CC + t], r0);
        r1 = fmaf(sc[m + 1], mem[(size_t)(m + 1) * CC + t], r1);
        r2 = fmaf(sc[m + 2], mem[(size_t)(m + 2) * CC + t], r2);
        r3 = fmaf(sc[m + 3], mem[(size_t)(m + 3) * CC + t], r3);
    }
    float r = (r0 + r1) + (r2 + r3);
    g[b * CC + t] = 1.f / (1.f + expf(-r));
}

// ---------------- K5: Wgbf[b][o][c] = bf16(g[b][c] * fusion_w[o][c]) ----------------
__global__ void k_wgbf(const float* __restrict__ g, const float* __restrict__ fw,
                       ushort* __restrict__ Wgbf) {
    int b = blockIdx.x >> 8, o = blockIdx.x & 255;
    int c = threadIdx.x;
    Wgbf[((size_t)blockIdx.x << 8) + c] = f2bf(g[(b << 8) + c] * fw[o * (2 * CC) + c]);
}

// ---------------- K6: main fused kernel ----------------
// grid 512 = B*H ; block 256 (4 waves). __launch_bounds__(256,4): VGPR<=128,
// LDS 39KB -> 4 blocks/CU = 4 waves/SIMD.
// NO X tile in LDS/regs: bfr built from global img; fp32 rescore re-reads
// img+mem from global at wrap-up. A-operand: 24 tiles of 32 rows (16KB),
// reg-staged (R[4]) into XOR-swizzled LDS dbuf (validated round 5: ~0 conflicts).
// Tiles 0..15 = membf (scores), 16..23 = Wgbf[b] (fusion).
// k-bijection: lane-group g16 owns k=64*g16+ks*8+j on A and B identically.
// C/D: col=lane&15, row=4*(lane>>4)+reg [verified].
__global__ __launch_bounds__(256, 4) void k_main(
        const float* __restrict__ img, const float* __restrict__ mem,
        const ushort* __restrict__ membf, const ushort* __restrict__ Wgbf,
        const float* __restrict__ mf, const float* __restrict__ fb,
        ushort* __restrict__ xbuf) {
    int bh = blockIdx.x;
    int b = bh >> 6, h = bh & 63;
    int t = threadIdx.x;
    int wave = __builtin_amdgcn_readfirstlane(t) >> 6;
    int lane = t & 63;
    int pxl  = lane & 15;
    int g16  = lane >> 4;
    int pxw  = wave * 16 + pxl;

    __shared__ __align__(16) char As[2][16384];     // 32 KB A-tile dbuf
    __shared__ float tkv[4][16][12];                // 3 KB
    __shared__ int   tki[4][16][12];                // 3 KB

    const char* mem_b = (const char*)membf;                     // tiles 0..15
    const char* wg_b  = (const char*)Wgbf + (size_t)b * 131072; // tiles 16..23

    s16x8 R[4];
#define TSRC(TI) ((TI) < 16 ? mem_b + (size_t)(TI) * 16384 : wg_b + (size_t)((TI) - 16) * 16384)
#define LOAD4(TI)                                                              \
    { const char* gb = TSRC(TI);                                               \
      _Pragma("unroll")                                                        \
      for (int j = 0; j < 4; j++) {                                            \
          int row = j * 8 + (t >> 5); int colb = (t & 31) * 16;                \
          R[j] = *(const s16x8*)(gb + row * 512 + colb);                       \
      } }
#define DSW4(BUF)                                                              \
    { char* lb = As[BUF];                                                      \
      _Pragma("unroll")                                                        \
      for (int j = 0; j < 4; j++) {                                            \
          int row = j * 8 + (t >> 5); int colb = (t & 31) * 16;                \
          *(s16x8*)(lb + row * 512 + (colb ^ (row << 4))) = R[j];              \
      } }
#define RD_A(LB, ROW, KS)                                                      \
    (*(const s16x8*)((LB) + (ROW) * 512 +                                      \
                     ((g16 * 128 + (KS) * 16) ^ ((ROW) << 4))))
#define MFMA_(A, B_, C_) __builtin_amdgcn_mfma_f32_16x16x32_bf16((A), (B_), (C_), 0, 0, 0)
#define TOPK_UPDATE(ACC, MB)                                                   \
    { _Pragma("unroll")                                                        \
      for (int r = 0; r < 4; r++) {                                            \
          float s = (ACC)[r]; int m = (MB) + r;                                \
          if (s > v2) {                                                        \
              if (s > v1) {                                                    \
                  if (s > v0) { v2 = v1; i2 = i1; v1 = v0; i1 = i0;            \
                                v0 = s;  i0 = m; }                             \
                  else        { v2 = v1; i2 = i1; v1 = s;  i1 = m; }           \
              } else          { v2 = s;  i2 = m; }                             \
          } } }

    // ---- prologue: issue tile0 loads; build bfr straight from global img ----
    LOAD4(0);
    const float* xsrc = img + ((size_t)b * CC + g16 * 64) * HWHW + h * 64 + pxw;
    s16x8 bfr[8];
#pragma unroll
    for (int ks = 0; ks < 8; ks++) {
        s16x8 v;
#pragma unroll
        for (int j = 0; j < 8; j++)
            v[j] = (short)f2bf(xsrc[(size_t)(ks * 8 + j) * HWHW]);
        bfr[ks] = v;
    }
    DSW4(0);
    LOAD4(1);
    __syncthreads();

    float v0 = -3e38f, v1 = -3e38f, v2 = -3e38f;
    int   i0 = 0, i1 = 0, i2 = 0;
    float a0 = 0.f, a1 = 0.f;
    int   b0 = 0, b1 = 0;
    int buf = 0;

    for (int tt = 0; tt < 24; tt++) {
        if (tt < 23) DSW4(buf ^ 1);          // stage tile tt+1 (consumes R)
        if (tt < 22) LOAD4(tt + 2);          // issue loads for tile tt+2

        if (tt == 16) {
            // ---- phase-A wrap-up ----
            tkv[wave][pxl][g16 * 3 + 0] = v0; tki[wave][pxl][g16 * 3 + 0] = i0;
            tkv[wave][pxl][g16 * 3 + 1] = v1; tki[wave][pxl][g16 * 3 + 1] = i1;
            tkv[wave][pxl][g16 * 3 + 2] = v2; tki[wave][pxl][g16 * 3 + 2] = i2;
            __syncthreads();
            float c0 = -3e38f, c1 = -3e38f, c2 = -3e38f, c3 = -3e38f;
            int   d0 = 0, d1 = 0, d2 = 0, d3 = 0;
#pragma unroll
            for (int q = 0; q < 12; q++) {
                float s = tkv[wave][pxl][q];
                int m = tki[wave][pxl][q];
                if (s > c3) {
                    if (s > c1) {
                        if (s > c0) { c3 = c2; d3 = d2; c2 = c1; d2 = d1; c1 = c0; d1 = d0; c0 = s; d0 = m; }
                        else        { c3 = c2; d3 = d2; c2 = c1; d2 = d1; c1 = s;  d1 = m; }
                    } else {
                        if (s > c2) { c3 = c2; d3 = d2; c2 = s;  d2 = m; }
                        else        { c3 = s;  d3 = m; }
                    }
                }
            }
            // ---- fp32 rescore from GLOBAL img + mem (exact inputs) ----
            float p0 = 0.f, p1 = 0.f, p2 = 0.f, p3 = 0.f;
            {
                const float4* m0p = (const float4*)(mem + (size_t)d0 * CC + g16 * 64);
                const float4* m1p = (const float4*)(mem + (size_t)d1 * CC + g16 * 64);
                const float4* m2p = (const float4*)(mem + (size_t)d2 * CC + g16 * 64);
                const float4* m3p = (const float4*)(mem + (size_t)d3 * CC + g16 * 64);
#pragma unroll 4
                for (int kk = 0; kk < 16; kk++) {
                    float4 av = m0p[kk], bv = m1p[kk], cv = m2p[kk], dv = m3p[kk];
                    float x0 = xsrc[(size_t)(kk * 4 + 0) * HWHW];
                    float x1 = xsrc[(size_t)(kk * 4 + 1) * HWHW];
                    float x2 = xsrc[(size_t)(kk * 4 + 2) * HWHW];
                    float x3 = xsrc[(size_t)(kk * 4 + 3) * HWHW];
                    p0 = fmaf(x0, av.x, p0); p0 = fmaf(x1, av.y, p0);
                    p0 = fmaf(x2, av.z, p0); p0 = fmaf(x3, av.w, p0);
                    p1 = fmaf(x0, bv.x, p1); p1 = fmaf(x1, bv.y, p1);
                    p1 = fmaf(x2, bv.z, p1); p1 = fmaf(x3, bv.w, p1);
                    p2 = fmaf(x0, cv.x, p2); p2 = fmaf(x1, cv.y, p2);
                    p2 = fmaf(x2, cv.z, p2); p2 = fmaf(x3, cv.w, p2);
                    p3 = fmaf(x0, dv.x, p3); p3 = fmaf(x1, dv.y, p3);
                    p3 = fmaf(x2, dv.z, p3); p3 = fmaf(x3, dv.w, p3);
                }
            }
#pragma unroll
            for (int st = 0; st < 2; st++) {
                int d = 16 << st;
                p0 += __shfl_xor(p0, d, 64);
                p1 += __shfl_xor(p1, d, 64);
                p2 += __shfl_xor(p2, d, 64);
                p3 += __shfl_xor(p3, d, 64);
            }
            float s0 = -3e38f, s1 = -3e38f;
#pragma unroll
            for (int q = 0; q < 4; q++) {
                float s = (q == 0) ? p0 : (q == 1) ? p1 : (q == 2) ? p2 : p3;
                int m = (q == 0) ? d0 : (q == 1) ? d1 : (q == 2) ? d2 : d3;
                if (s > s1) {
                    if (s > s0) { s1 = s0; b1 = b0; s0 = s; b0 = m; }
                    else        { s1 = s;  b1 = m; }
                }
            }
            float e = expf(s1 - s0);
            a0 = 1.f / (1.f + e);
            a1 = e * a0;
        }

        const char* lb = As[buf];
        if (tt < 16) {
            // ---- score tile: 32 m-rows = 2 sub-tiles ----
            int tbase = tt * 32;
            f32x4 acc0 = {0.f, 0.f, 0.f, 0.f};
            f32x4 acc1 = {0.f, 0.f, 0.f, 0.f};
#pragma unroll
            for (int ch = 0; ch < 2; ch++) {
                s16x8 af0[4], af1[4];
#pragma unroll
                for (int ks = 0; ks < 4; ks++) {
                    af0[ks] = RD_A(lb, pxl,      ch * 4 + ks);
                    af1[ks] = RD_A(lb, 16 + pxl, ch * 4 + ks);
                }
#pragma unroll
                for (int ks = 0; ks < 4; ks++) {
                    acc0 = MFMA_(af0[ks], bfr[ch * 4 + ks], acc0);
                    acc1 = MFMA_(af1[ks], bfr[ch * 4 + ks], acc1);
                }
            }
            TOPK_UPDATE(acc0, tbase + 4 * g16);
            TOPK_UPDATE(acc1, tbase + 16 + 4 * g16);
        } else {
            // ---- fusion tile: 32 o-rows = 2 sub-tiles + fused epilogue ----
            int obase = (tt - 16) * 32;
            f32x4 acc0 = {0.f, 0.f, 0.f, 0.f};
            f32x4 acc1 = {0.f, 0.f, 0.f, 0.f};
#pragma unroll
            for (int ch = 0; ch < 2; ch++) {
                s16x8 af0[4], af1[4];
#pragma unroll
                for (int ks = 0; ks < 4; ks++) {
                    af0[ks] = RD_A(lb, pxl,      ch * 4 + ks);
                    af1[ks] = RD_A(lb, 16 + pxl, ch * 4 + ks);
                }
#pragma unroll
                for (int ks = 0; ks < 4; ks++) {
                    acc0 = MFMA_(af0[ks], bfr[ch * 4 + ks], acc0);
                    acc1 = MFMA_(af1[ks], bfr[ch * 4 + ks], acc1);
                }
            }
#pragma unroll
            for (int half = 0; half < 2; half++) {
                f32x4 acc = half ? acc1 : acc0;
                int ob = obase + half * 16 + 4 * g16;
                float4 m0v = *(const float4*)(mf + (size_t)b0 * CC + ob);
                float4 m1v = *(const float4*)(mf + (size_t)b1 * CC + ob);
                float4 fbv = *(const float4*)(fb + ob);
                float vr0 = acc[0] + a0 * m0v.x + a1 * m1v.x + fbv.x;
                float vr1 = acc[1] + a0 * m0v.y + a1 * m1v.y + fbv.y;
                float vr2 = acc[2] + a0 * m0v.z + a1 * m1v.z + fbv.z;
                float vr3 = acc[3] + a0 * m0v.w + a1 * m1v.w + fbv.w;
                vr0 = vr0 > 0.f ? vr0 : 0.2f * vr0;
                vr1 = vr1 > 0.f ? vr1 : 0.2f * vr1;
                vr2 = vr2 > 0.f ? vr2 : 0.2f * vr2;
                vr3 = vr3 > 0.f ? vr3 : 0.2f * vr3;
                ushort* dst = xbuf + ((size_t)(b * CC + ob)) * HWHW + h * 64 + pxw;
                dst[0 * HWHW] = f2bf(vr0); dst[1 * HWHW] = f2bf(vr1);
                dst[2 * HWHW] = f2bf(vr2); dst[3 * HWHW] = f2bf(vr3);
            }
        }
        __syncthreads();
        buf ^= 1;
    }
}

// ---------------- K7: depthwise dilated 3x3 (d=2) + bias + leaky (bf16 in) --------
__global__ void k_dw(const ushort* __restrict__ x, const float* __restrict__ dw,
                     const float* __restrict__ db, float* __restrict__ out) {
    int bc = blockIdx.x;
    int c = bc & 255;
    __shared__ float plane[HWHW];
    const ushort* src = x + (size_t)bc * HWHW;
    int t = threadIdx.x;
#pragma unroll
    for (int k = 0; k < 16; k++) plane[t + 256 * k] = bf2f(src[t + 256 * k]);
    __syncthreads();
    float w[9];
#pragma unroll
    for (int j = 0; j < 9; j++) w[j] = dw[c * 9 + j];
    float bias = db[c];
    float* dst = out + (size_t)bc * HWHW;
#pragma unroll
    for (int k = 0; k < 16; k++) {
        int p = t + 256 * k;
        int hh = p >> 6, ww = p & 63;
        float s = bias;
#pragma unroll
        for (int u = 0; u < 3; u++) {
            int h2 = hh + 2 * (u - 1);
            if ((unsigned)h2 < 64u) {
#pragma unroll
                for (int v = 0; v < 3; v++) {
                    int w2 = ww + 2 * (v - 1);
                    if ((unsigned)w2 < 64u) s = fmaf(plane[h2 * 64 + w2], w[u * 3 + v], s);
                }
            }
        }
        dst[p] = s > 0.f ? s : 0.2f * s;
    }
}

extern "C" void kernel_launch(void* const* d_in, const int* in_sizes, int n_in,
                              void* d_out, int out_size, void* d_ws, size_t ws_size,
                              hipStream_t stream) {
    const float* img = (const float*)d_in[0];
    const float* mem = (const float*)d_in[1];
    const float* fw  = (const float*)d_in[2];
    const float* fb  = (const float*)d_in[3];
    const float* dw  = (const float*)d_in[4];
    const float* db  = (const float*)d_in[5];
    float* out = (float*)d_out;
    float* ws = (float*)d_ws;

    float*  IG    = ws;                                   // 2048
    float*  gbuf  = ws + 2048;                            // 2048
    float*  mf    = ws + 4096;                            // 131072
    ushort* membf = (ushort*)(ws + 135168);               // 131072 u16
    ushort* Wgbf  = (ushort*)(ws + 135168 + 65536);       // 524288 u16
    ushort* xb    = (ushort*)(ws + 135168 + 65536 + 262144); // 8388608 u16 (16 MB)

    k_pre   <<<2240,    256, 0, stream>>>(img, mem, fw, IG, membf, mf);
    k_global<<<BB,      256, 0, stream>>>(IG, mem, gbuf);
    k_wgbf  <<<BB * CC, 256, 0, stream>>>(gbuf, fw, Wgbf);
    k_main  <<<BB * HH, 256, 0, stream>>>(img, mem, membf, Wgbf, mf, fb, xb);
    k_dw    <<<BB * CC, 256, 0, stream>>>(xb, dw, db, out);
}

// Round 8
// 190.422 us; speedup vs baseline: 1.5793x; 1.5793x over previous
//
#include <hip/hip_runtime.h>
#include <hip/hip_bf16.h>

#define BB 8
#define CC 256
#define HH 64
#define WW 64
#define MM 512
#define HWHW 4096

typedef __attribute__((ext_vector_type(4))) float f32x4;
typedef __attribute__((ext_vector_type(8))) short s16x8;

static __device__ __forceinline__ ushort f2bf(float f) {
    unsigned u = __float_as_uint(f);
    unsigned r = ((u >> 16) & 1u) + 0x7fffu;      // RNE
    return (ushort)((u + r) >> 16);
}
static __device__ __forceinline__ float bf2f(ushort u) {
    return __uint_as_float(((unsigned)u) << 16);
}

// ---------------- K_pre: fused {ig | prep | mf} ----------------
__global__ void k_pre(const float* __restrict__ img, const float* __restrict__ mem,
                      const float* __restrict__ fw, float* __restrict__ IG,
                      ushort* __restrict__ membf, float* __restrict__ mf) {
    int bid = blockIdx.x;
    int t = threadIdx.x;
    if (bid < 2048) {
        const float4* p = (const float4*)(img + (size_t)bid * HWHW);
        float s = 0.f;
#pragma unroll
        for (int k = 0; k < 4; k++) {
            float4 v = p[t + 256 * k];
            s += v.x + v.y + v.z + v.w;
        }
#pragma unroll
        for (int off = 32; off > 0; off >>= 1) s += __shfl_down(s, off);
        __shared__ float red[4];
        int wave = t >> 6, lane = t & 63;
        if (lane == 0) red[wave] = s;
        __syncthreads();
        if (t == 0) IG[bid] = (red[0] + red[1] + red[2] + red[3]) * (1.f / 4096.f);
    } else if (bid < 2176) {
        int i = ((bid - 2048) * 256 + t) * 4;
        float4 v = *(const float4*)(mem + i);
        ushort4 o;
        o.x = f2bf(v.x); o.y = f2bf(v.y); o.z = f2bf(v.z); o.w = f2bf(v.w);
        *(ushort4*)(membf + i) = o;
    } else {
        int m0 = (bid - 2176) * 8;
        __shared__ float mrow[8][CC];
#pragma unroll
        for (int j = 0; j < 8; j++) mrow[j][t] = mem[(size_t)(m0 + j) * CC + t];
        __syncthreads();
        const float4* fwr = (const float4*)(fw + (size_t)t * (2 * CC) + CC);
        float acc[8];
#pragma unroll
        for (int j = 0; j < 8; j++) acc[j] = 0.f;
#pragma unroll 8
        for (int ci = 0; ci < 64; ci++) {
            float4 fv = fwr[ci];
#pragma unroll
            for (int j = 0; j < 8; j++) {
                acc[j] = fmaf(mrow[j][ci * 4 + 0], fv.x, acc[j]);
                acc[j] = fmaf(mrow[j][ci * 4 + 1], fv.y, acc[j]);
                acc[j] = fmaf(mrow[j][ci * 4 + 2], fv.z, acc[j]);
                acc[j] = fmaf(mrow[j][ci * 4 + 3], fv.w, acc[j]);
            }
        }
#pragma unroll
        for (int j = 0; j < 8; j++) mf[(size_t)(m0 + j) * CC + t] = acc[j];
    }
}

// ---------------- K2: gate g = sigmoid(softmax(IG@M^T)@M + IG) ----------------
__global__ void k_global(const float* __restrict__ IG, const float* __restrict__ mem,
                         float* __restrict__ g) {
    int b = blockIdx.x;
    int t = threadIdx.x;
    __shared__ float ig[CC];
    __shared__ float sc[MM];
    __shared__ float red[256];
    ig[t] = IG[b * CC + t];
    __syncthreads();
#pragma unroll
    for (int half = 0; half < 2; half++) {
        int m = t + half * 256;
        const float4* mr = (const float4*)(mem + (size_t)m * CC);
        const float4* igr = (const float4*)ig;
        float s0 = 0.f, s1 = 0.f, s2 = 0.f, s3 = 0.f;
#pragma unroll 8
        for (int ci = 0; ci < 64; ci++) {
            float4 mv = mr[ci];
            float4 iv = igr[ci];
            s0 = fmaf(mv.x, iv.x, s0); s1 = fmaf(mv.y, iv.y, s1);
            s2 = fmaf(mv.z, iv.z, s2); s3 = fmaf(mv.w, iv.w, s3);
        }
        sc[m] = (s0 + s1) + (s2 + s3);
    }
    __syncthreads();
    red[t] = fmaxf(sc[t], sc[t + 256]);
    __syncthreads();
    for (int o = 128; o > 0; o >>= 1) {
        if (t < o) red[t] = fmaxf(red[t], red[t + o]);
        __syncthreads();
    }
    float mx = red[0];
    __syncthreads();
    float e0 = expf(sc[t] - mx), e1 = expf(sc[t + 256] - mx);
    red[t] = e0 + e1;
    __syncthreads();
    for (int o = 128; o > 0; o >>= 1) {
        if (t < o) red[t] += red[t + o];
        __syncthreads();
    }
    float inv = 1.f / red[0];
    sc[t] = e0 * inv; sc[t + 256] = e1 * inv;
    __syncthreads();
    float r0 = ig[t], r1 = 0.f, r2 = 0.f, r3 = 0.f;
#pragma unroll 8
    for (int m = 0; m < MM; m += 4) {
        r0 = fmaf(sc[m + 0], mem[(size_t)(m + 0) * CC + t], r0);
        r1 = fmaf(sc[m + 1], mem[(size_t)(m + 1) * CC + t], r1);
        r2 = fmaf(sc[m + 2], mem[(size_t)(m + 2) * CC + t], r2);
        r3 = fmaf(sc[m + 3], mem[(size_t)(m + 3) * CC + t], r3);
    }
    float r = (r0 + r1) + (r2 + r3);
    g[b * CC + t] = 1.f / (1.f + expf(-r));
}

// ---------------- K5: Wgbf[b][o][c] = bf16(g[b][c] * fusion_w[o][c]) ----------------
__global__ void k_wgbf(const float* __restrict__ g, const float* __restrict__ fw,
                       ushort* __restrict__ Wgbf) {
    int b = blockIdx.x >> 8, o = blockIdx.x & 255;
    int c = threadIdx.x;
    Wgbf[((size_t)blockIdx.x << 8) + c] = f2bf(g[(b << 8) + c] * fw[o * (2 * CC) + c]);
}

// ---------------- K6: main fused kernel ----------------
// grid 512 = B*H ; block 256 (4 waves). __launch_bounds__(256,2): ~128-VGPR-class
// budget (never spilled at this class), LDS 70.5KB -> 2 blocks/CU (= grid cap).
// 12 tiles of 64 rows (32KB): 0..7 membf (scores), 8..11 Wgbf[b] (fusion).
// Reg-staged (R[8]) -> XOR-swizzled LDS dbuf; DSW/RD_A pair = round-5 mapping
// (measured low-conflict): swz (row&31)<<4, col = g16*16 + ks*64.
// k-bijection: lane-group g16 owns k = ks*32 + g16*8 + j on A and B identically.
// No X tile anywhere: bfr from global img; fp32 rescore re-reads img+mem.
// C/D: col=lane&15, row=4*(lane>>4)+reg [verified].
__global__ __launch_bounds__(256, 2) void k_main(
        const float* __restrict__ img, const float* __restrict__ mem,
        const ushort* __restrict__ membf, const ushort* __restrict__ Wgbf,
        const float* __restrict__ mf, const float* __restrict__ fb,
        ushort* __restrict__ xbuf) {
    int bh = blockIdx.x;
    int b = bh >> 6, h = bh & 63;
    int t = threadIdx.x;
    int wave = __builtin_amdgcn_readfirstlane(t) >> 6;
    int lane = t & 63;
    int pxl  = lane & 15;
    int g16  = lane >> 4;
    int pxw  = wave * 16 + pxl;

    __shared__ __align__(16) char As[2][32768];     // 64 KB A-tile dbuf
    __shared__ float tkv[4][16][12];                // 3 KB
    __shared__ int   tki[4][16][12];                // 3 KB

    const char* mem_b = (const char*)membf;                     // tiles 0..7
    const char* wg_b  = (const char*)Wgbf + (size_t)b * 131072; // tiles 8..11

    s16x8 R[8];
#define TSRC(TI) ((TI) < 8 ? mem_b + (size_t)(TI) * 32768 : wg_b + (size_t)((TI) - 8) * 32768)
#define LOAD8(TI)                                                              \
    { const char* gb = TSRC(TI);                                               \
      _Pragma("unroll")                                                        \
      for (int j = 0; j < 8; j++) {                                            \
          int row = j * 8 + (t >> 5); int colb = (t & 31) * 16;                \
          R[j] = *(const s16x8*)(gb + row * 512 + colb);                       \
      } }
#define DSW8(BUF)                                                              \
    { char* lb = As[BUF];                                                      \
      _Pragma("unroll")                                                        \
      for (int j = 0; j < 8; j++) {                                            \
          int row = j * 8 + (t >> 5); int colb = (t & 31) * 16;                \
          *(s16x8*)(lb + row * 512 + (colb ^ ((row & 31) << 4))) = R[j];       \
      } }
#define RD_A(LB, ROW, KS)                                                      \
    (*(const s16x8*)((LB) + (ROW) * 512 +                                      \
                     ((g16 * 16 + (KS) * 64) ^ (((ROW) & 31) << 4))))
#define MFMA_(A, B_, C_) __builtin_amdgcn_mfma_f32_16x16x32_bf16((A), (B_), (C_), 0, 0, 0)
#define TOPK_UPDATE(ACC, MB)                                                   \
    { _Pragma("unroll")                                                        \
      for (int r = 0; r < 4; r++) {                                            \
          float s = (ACC)[r]; int m = (MB) + r;                                \
          if (s > v2) {                                                        \
              if (s > v1) {                                                    \
                  if (s > v0) { v2 = v1; i2 = i1; v1 = v0; i1 = i0;            \
                                v0 = s;  i0 = m; }                             \
                  else        { v2 = v1; i2 = i1; v1 = s;  i1 = m; }           \
              } else          { v2 = s;  i2 = m; }                             \
          } } }

    // ---- prologue: issue tile0 loads; build bfr from global img (interleaved k) ----
    LOAD8(0);
    const float* xsrc = img + (size_t)b * CC * HWHW + h * 64 + pxw;
    s16x8 bfr[8];
#pragma unroll
    for (int ks = 0; ks < 8; ks++) {
        s16x8 v;
#pragma unroll
        for (int j = 0; j < 8; j++)
            v[j] = (short)f2bf(xsrc[(size_t)(ks * 32 + g16 * 8 + j) * HWHW]);
        bfr[ks] = v;
    }
    DSW8(0);
    LOAD8(1);
    __syncthreads();

    float v0 = -3e38f, v1 = -3e38f, v2 = -3e38f;
    int   i0 = 0, i1 = 0, i2 = 0;
    float a0 = 0.f, a1 = 0.f;
    int   b0 = 0, b1 = 0;
    int buf = 0;

    for (int tt = 0; tt < 12; tt++) {
        if (tt < 11) DSW8(buf ^ 1);          // stage tile tt+1 (consumes R)
        if (tt < 10) LOAD8(tt + 2);          // issue loads for tile tt+2

        if (tt == 8) {
            // ---- phase-A wrap-up ----
            tkv[wave][pxl][g16 * 3 + 0] = v0; tki[wave][pxl][g16 * 3 + 0] = i0;
            tkv[wave][pxl][g16 * 3 + 1] = v1; tki[wave][pxl][g16 * 3 + 1] = i1;
            tkv[wave][pxl][g16 * 3 + 2] = v2; tki[wave][pxl][g16 * 3 + 2] = i2;
            __syncthreads();
            float c0 = -3e38f, c1 = -3e38f, c2 = -3e38f, c3 = -3e38f;
            int   d0 = 0, d1 = 0, d2 = 0, d3 = 0;
#pragma unroll
            for (int q = 0; q < 12; q++) {
                float s = tkv[wave][pxl][q];
                int m = tki[wave][pxl][q];
                if (s > c3) {
                    if (s > c1) {
                        if (s > c0) { c3 = c2; d3 = d2; c2 = c1; d2 = d1; c1 = c0; d1 = d0; c0 = s; d0 = m; }
                        else        { c3 = c2; d3 = d2; c2 = c1; d2 = d1; c1 = s;  d1 = m; }
                    } else {
                        if (s > c2) { c3 = c2; d3 = d2; c2 = s;  d2 = m; }
                        else        { c3 = s;  d3 = m; }
                    }
                }
            }
            // ---- fp32 rescore from GLOBAL img+mem over this lane's interleaved c-slice ----
            float p0 = 0.f, p1 = 0.f, p2 = 0.f, p3 = 0.f;
#pragma unroll 2
            for (int ks = 0; ks < 8; ks++) {
                int cb = ks * 32 + g16 * 8;
                float xv[8];
#pragma unroll
                for (int j = 0; j < 8; j++) xv[j] = xsrc[(size_t)(cb + j) * HWHW];
                const float4* m0p = (const float4*)(mem + (size_t)d0 * CC + cb);
                const float4* m1p = (const float4*)(mem + (size_t)d1 * CC + cb);
                const float4* m2p = (const float4*)(mem + (size_t)d2 * CC + cb);
                const float4* m3p = (const float4*)(mem + (size_t)d3 * CC + cb);
#pragma unroll
                for (int hf = 0; hf < 2; hf++) {
                    float4 u0 = m0p[hf], u1 = m1p[hf], u2 = m2p[hf], u3 = m3p[hf];
                    float x0 = xv[hf * 4 + 0], x1 = xv[hf * 4 + 1];
                    float x2 = xv[hf * 4 + 2], x3 = xv[hf * 4 + 3];
                    p0 = fmaf(x0, u0.x, p0); p0 = fmaf(x1, u0.y, p0);
                    p0 = fmaf(x2, u0.z, p0); p0 = fmaf(x3, u0.w, p0);
                    p1 = fmaf(x0, u1.x, p1); p1 = fmaf(x1, u1.y, p1);
                    p1 = fmaf(x2, u1.z, p1); p1 = fmaf(x3, u1.w, p1);
                    p2 = fmaf(x0, u2.x, p2); p2 = fmaf(x1, u2.y, p2);
                    p2 = fmaf(x2, u2.z, p2); p2 = fmaf(x3, u2.w, p2);
                    p3 = fmaf(x0, u3.x, p3); p3 = fmaf(x1, u3.y, p3);
                    p3 = fmaf(x2, u3.z, p3); p3 = fmaf(x3, u3.w, p3);
                }
            }
#pragma unroll
            for (int st = 0; st < 2; st++) {
                int d = 16 << st;
                p0 += __shfl_xor(p0, d, 64);
                p1 += __shfl_xor(p1, d, 64);
                p2 += __shfl_xor(p2, d, 64);
                p3 += __shfl_xor(p3, d, 64);
            }
            float s0 = -3e38f, s1 = -3e38f;
#pragma unroll
            for (int q = 0; q < 4; q++) {
                float s = (q == 0) ? p0 : (q == 1) ? p1 : (q == 2) ? p2 : p3;
                int m = (q == 0) ? d0 : (q == 1) ? d1 : (q == 2) ? d2 : d3;
                if (s > s1) {
                    if (s > s0) { s1 = s0; b1 = b0; s0 = s; b0 = m; }
                    else        { s1 = s;  b1 = m; }
                }
            }
            float e = expf(s1 - s0);
            a0 = 1.f / (1.f + e);
            a1 = e * a0;
        }

        const char* lb = As[buf];
        if (tt < 8) {
            // ---- score tile: 64 m-rows = 2 row-pair sub-tiles ----
            int tbase = tt * 64;
#pragma unroll
            for (int sp = 0; sp < 2; sp++) {
                int r0 = sp * 32 + pxl, r1 = sp * 32 + 16 + pxl;
                f32x4 acc0 = {0.f, 0.f, 0.f, 0.f};
                f32x4 acc1 = {0.f, 0.f, 0.f, 0.f};
#pragma unroll
                for (int ch = 0; ch < 4; ch++) {
                    s16x8 af0[2], af1[2];
#pragma unroll
                    for (int ks = 0; ks < 2; ks++) {
                        af0[ks] = RD_A(lb, r0, ch * 2 + ks);
                        af1[ks] = RD_A(lb, r1, ch * 2 + ks);
                    }
#pragma unroll
                    for (int ks = 0; ks < 2; ks++) {
                        acc0 = MFMA_(af0[ks], bfr[ch * 2 + ks], acc0);
                        acc1 = MFMA_(af1[ks], bfr[ch * 2 + ks], acc1);
                    }
                }
                TOPK_UPDATE(acc0, tbase + sp * 32 + 4 * g16);
                TOPK_UPDATE(acc1, tbase + sp * 32 + 16 + 4 * g16);
            }
        } else {
            // ---- fusion tile: 64 o-rows = 2 row-pair sub-tiles + fused epilogue ----
            int obase = (tt - 8) * 64;
#pragma unroll
            for (int sp = 0; sp < 2; sp++) {
                int r0 = sp * 32 + pxl, r1 = sp * 32 + 16 + pxl;
                f32x4 acc0 = {0.f, 0.f, 0.f, 0.f};
                f32x4 acc1 = {0.f, 0.f, 0.f, 0.f};
#pragma unroll
                for (int ch = 0; ch < 4; ch++) {
                    s16x8 af0[2], af1[2];
#pragma unroll
                    for (int ks = 0; ks < 2; ks++) {
                        af0[ks] = RD_A(lb, r0, ch * 2 + ks);
                        af1[ks] = RD_A(lb, r1, ch * 2 + ks);
                    }
#pragma unroll
                    for (int ks = 0; ks < 2; ks++) {
                        acc0 = MFMA_(af0[ks], bfr[ch * 2 + ks], acc0);
                        acc1 = MFMA_(af1[ks], bfr[ch * 2 + ks], acc1);
                    }
                }
#pragma unroll
                for (int half = 0; half < 2; half++) {
                    f32x4 acc = half ? acc1 : acc0;
                    int ob = obase + sp * 32 + half * 16 + 4 * g16;
                    float4 m0v = *(const float4*)(mf + (size_t)b0 * CC + ob);
                    float4 m1v = *(const float4*)(mf + (size_t)b1 * CC + ob);
                    float4 fbv = *(const float4*)(fb + ob);
                    float vr0 = acc[0] + a0 * m0v.x + a1 * m1v.x + fbv.x;
                    float vr1 = acc[1] + a0 * m0v.y + a1 * m1v.y + fbv.y;
                    float vr2 = acc[2] + a0 * m0v.z + a1 * m1v.z + fbv.z;
                    float vr3 = acc[3] + a0 * m0v.w + a1 * m1v.w + fbv.w;
                    vr0 = vr0 > 0.f ? vr0 : 0.2f * vr0;
                    vr1 = vr1 > 0.f ? vr1 : 0.2f * vr1;
                    vr2 = vr2 > 0.f ? vr2 : 0.2f * vr2;
                    vr3 = vr3 > 0.f ? vr3 : 0.2f * vr3;
                    ushort* dst = xbuf + ((size_t)(b * CC + ob)) * HWHW + h * 64 + pxw;
                    dst[0 * HWHW] = f2bf(vr0); dst[1 * HWHW] = f2bf(vr1);
                    dst[2 * HWHW] = f2bf(vr2); dst[3 * HWHW] = f2bf(vr3);
                }
            }
        }
        __syncthreads();
        buf ^= 1;
    }
}

// ---------------- K7: depthwise dilated 3x3 (d=2) + bias + leaky (bf16 in) --------
__global__ void k_dw(const ushort* __restrict__ x, const float* __restrict__ dw,
                     const float* __restrict__ db, float* __restrict__ out) {
    int bc = blockIdx.x;
    int c = bc & 255;
    __shared__ float plane[HWHW];
    const ushort* src = x + (size_t)bc * HWHW;
    int t = threadIdx.x;
#pragma unroll
    for (int k = 0; k < 16; k++) plane[t + 256 * k] = bf2f(src[t + 256 * k]);
    __syncthreads();
    float w[9];
#pragma unroll
    for (int j = 0; j < 9; j++) w[j] = dw[c * 9 + j];
    float bias = db[c];
    float* dst = out + (size_t)bc * HWHW;
#pragma unroll
    for (int k = 0; k < 16; k++) {
        int p = t + 256 * k;
        int hh = p >> 6, ww = p & 63;
        float s = bias;
#pragma unroll
        for (int u = 0; u < 3; u++) {
            int h2 = hh + 2 * (u - 1);
            if ((unsigned)h2 < 64u) {
#pragma unroll
                for (int v = 0; v < 3; v++) {
                    int w2 = ww + 2 * (v - 1);
                    if ((unsigned)w2 < 64u) s = fmaf(plane[h2 * 64 + w2], w[u * 3 + v], s);
                }
            }
        }
        dst[p] = s > 0.f ? s : 0.2f * s;
    }
}

extern "C" void kernel_launch(void* const* d_in, const int* in_sizes, int n_in,
                              void* d_out, int out_size, void* d_ws, size_t ws_size,
                              hipStream_t stream) {
    const float* img = (const float*)d_in[0];
    const float* mem = (const float*)d_in[1];
    const float* fw  = (const float*)d_in[2];
    const float* fb  = (const float*)d_in[3];
    const float* dw  = (const float*)d_in[4];
    const float* db  = (const float*)d_in[5];
    float* out = (float*)d_out;
    float* ws = (float*)d_ws;

    float*  IG    = ws;                                   // 2048
    float*  gbuf  = ws + 2048;                            // 2048
    float*  mf    = ws + 4096;                            // 131072
    ushort* membf = (ushort*)(ws + 135168);               // 131072 u16
    ushort* Wgbf  = (ushort*)(ws + 135168 + 65536);       // 524288 u16
    ushort* xb    = (ushort*)(ws + 135168 + 65536 + 262144); // 8388608 u16 (16 MB)

    k_pre   <<<2240,    256, 0, stream>>>(img, mem, fw, IG, membf, mf);
    k_global<<<BB,      256, 0, stream>>>(IG, mem, gbuf);
    k_wgbf  <<<BB * CC, 256, 0, stream>>>(gbuf, fw, Wgbf);
    k_main  <<<BB * HH, 256, 0, stream>>>(img, mem, membf, Wgbf, mf, fb, xb);
    k_dw    <<<BB * CC, 256, 0, stream>>>(xb, dw, db, out);
}